// Round 4
// baseline (542.671 us; speedup 1.0000x reference)
//
#include <hip/hip_runtime.h>

// Sinkhorn matching loss: B=16,T=64,N=256,D=128; 1024 frames.
// PERSISTENT version: 256 blocks (1/CU), each block processes 4 frames.
// Per frame: stage S,T bf16 in LDS; cdist via mfma_f32_16x16x32_bf16; K=exp(-cost/tau)
// in regs (acc[16] f32x4 / wave row-block); 10 Sinkhorn iters; final <uKv,cost>.
//
// Round-7 changes (round-6 post-mortem: 274us, VALUBusy 61%, LDS pipe per-CU
// co-limiting at ~800 DS ops/iter (16 waves x ~50) + serial 16-read tail):
//  1. u-step butterfly fully DPP: xor4/8 ds_swizzle -> ROW_HALF_MIRROR(l^7) +
//     ROW_MIRROR(l^15). Exact 16-lane sums, zero LDS.
//  2. v-step xor16 -> permlane16_swap (VALU; __has_builtin-guarded with
//     ds_swizzle fallback).
//  3. cross-wave colsum via ds_add_f32 (atomicAdd on LDS vacc[256]); tail is
//     now 1 read + rezero + rcp + 1 write (was 16-read serial chain). Atomic
//     order nondeterminism already accepted (global atomicAdd in epilogue).
//  4. MUF/(x+EPS) via v_rcp_f32 + exact *2^-8 (<=1ulp) instead of exact-div
//     sequences (~9 instr -> 3).
// DS ops/iter/wave ~50 -> ~22.
//
// HARD RULES:
//  - every loop indexing acc[] fully unrolled (runtime index -> scratch).
//  - register budget: 64 acc (AGPR) + arch VGPR <= 128 total (4 waves/EU cap).
//    NO vector state may live across a sinkhorn iteration boundary.

typedef __bf16 bf16x8 __attribute__((ext_vector_type(8)));
typedef __bf16 bf16x4 __attribute__((ext_vector_type(4)));
typedef float floatx4 __attribute__((ext_vector_type(4)));

constexpr int N = 256;
constexpr int D = 128;
constexpr int NITER = 10;
#define TAUF 0.05f
#define EPSF 1e-8f
#define MUF  (1.0f / 256.0f)

constexpr int SRW = 136;              // bf16 row stride: rows step 4 banks -> 2-way (free)
constexpr int STAGE_B = N * SRW * 2;  // 69632 bytes per staged array
constexpr int VPAD = 20;              // vshT row stride (floats): 80B, 16B-aligned, 2-way banks

__device__ __forceinline__ float bc_f(int x) { return __builtin_bit_cast(float, x); }
__device__ __forceinline__ int   bc_i(float x) { return __builtin_bit_cast(int, x); }

// xor1 within quads: quad_perm [1,0,3,2] = 0xB1. Pure VALU (DPP).
__device__ __forceinline__ float qp_xor1_add(float v) {
    return v + bc_f(__builtin_amdgcn_update_dpp(0, bc_i(v), 0xB1, 0xF, 0xF, true));
}
// xor2 within quads: quad_perm [2,3,0,1] = 0x4E.
__device__ __forceinline__ float qp_xor2_add(float v) {
    return v + bc_f(__builtin_amdgcn_update_dpp(0, bc_i(v), 0x4E, 0xF, 0xF, true));
}
// l^7 within octets: DPP ROW_HALF_MIRROR (0x141). After xor1+xor2 this pairs
// quads -> octet sums.
__device__ __forceinline__ float qp_xor7_add(float v) {
    return v + bc_f(__builtin_amdgcn_update_dpp(0, bc_i(v), 0x141, 0xF, 0xF, true));
}
// l^15 within rows of 16: DPP ROW_MIRROR (0x140). Pairs octets -> 16-lane sums.
__device__ __forceinline__ float qp_xor15_add(float v) {
    return v + bc_f(__builtin_amdgcn_update_dpp(0, bc_i(v), 0x140, 0xF, 0xF, true));
}
// xor4/8/16 via ds_swizzle BitMode: (mask<<10)|0x1F (fallback path only)
template <int PAT>
__device__ __forceinline__ float swz_xor_add(float v) {
    return v + bc_f(__builtin_amdgcn_ds_swizzle(bc_i(v), PAT));
}
// xor16 via permlane16_swap (VALU): r[0]+r[1] == v + v[lane^16]
__device__ __forceinline__ float xor16_add(float v) {
#if __has_builtin(__builtin_amdgcn_permlane16_swap)
    auto r = __builtin_amdgcn_permlane16_swap(bc_i(v), bc_i(v), false, false);
    return bc_f(r[0]) + bc_f(r[1]);
#else
    return swz_xor_add<0x401F>(v);
#endif
}
// xor32 via permlane32_swap (VALU): r[0]+r[1] == v + v[lane^32]
__device__ __forceinline__ float xor32_add(float v) {
    auto r = __builtin_amdgcn_permlane32_swap(bc_i(v), bc_i(v), false, false);
    return bc_f(r[0]) + bc_f(r[1]);
}
// MUF/(x+EPS) via v_rcp_f32 (~1ulp) + exact *2^-8 scale
__device__ __forceinline__ float mu_over(float x) {
#if __has_builtin(__builtin_amdgcn_rcpf)
    return MUF * __builtin_amdgcn_rcpf(x + EPSF);
#else
    return MUF / (x + EPSF);
#endif
}

__global__ __launch_bounds__(1024) __attribute__((amdgpu_waves_per_eu(4, 4)))
void sinkhorn_kernel(const float* __restrict__ Sg, const float* __restrict__ Tg,
                     float* __restrict__ out)
{
    __shared__ __align__(16) char stage[2 * STAGE_B];   // Sb,Tb (live across frames: prefetch target)
    __shared__ __align__(16) float vshT[16][VPAD];      // v transposed: vshT[c&15][c>>4]
    __shared__ __align__(16) float vacc[N];             // ds_add_f32 colsum accumulator
    __shared__ float s2[N], t2[N], wsum[16];

    __bf16 (*Sb)[SRW] = (__bf16(*)[SRW])stage;
    __bf16 (*Tb)[SRW] = (__bf16(*)[SRW])(stage + STAGE_B);

    const int tid  = threadIdx.x;
    const int lane = tid & 63;
    const int w    = tid >> 6;     // wave 0..15 -> K rows [16w, 16w+16)
    const int l15  = lane & 15;
    const int q    = lane >> 4;    // quad 0..3
    const int ln   = tid >> 2;     // frame-0 staging row 0..255
    const int lq   = tid & 3;      // frame-0 staging d-chunk of 32 floats

    const size_t fbase = (size_t)blockIdx.x * 4;

    // ---- frame 0: direct staging (chunks back-to-back: full line reuse) ----
    {
        const float4* Sv = (const float4*)(Sg + fbase * (size_t)(N * D));
        const float4* Tv = (const float4*)(Tg + fbase * (size_t)(N * D));
        float sqS = 0.f, sqT = 0.f;
#pragma unroll 2
        for (int t = 0; t < 8; ++t) {
            float4 a = Sv[ln * 32 + lq * 8 + t];
            float4 b = Tv[ln * 32 + lq * 8 + t];
            __bf16 a0 = (__bf16)a.x, a1 = (__bf16)a.y, a2 = (__bf16)a.z, a3 = (__bf16)a.w;
            __bf16 b0 = (__bf16)b.x, b1 = (__bf16)b.y, b2 = (__bf16)b.z, b3 = (__bf16)b.w;
            float fa0 = (float)a0, fa1 = (float)a1, fa2 = (float)a2, fa3 = (float)a3;
            float fb0 = (float)b0, fb1 = (float)b1, fb2 = (float)b2, fb3 = (float)b3;
            sqS += fa0 * fa0 + fa1 * fa1 + fa2 * fa2 + fa3 * fa3;
            sqT += fb0 * fb0 + fb1 * fb1 + fb2 * fb2 + fb3 * fb3;
            bf16x4 pa = {a0, a1, a2, a3};
            bf16x4 pb = {b0, b1, b2, b3};
            *(bf16x4*)&Sb[ln][lq * 32 + t * 4] = pa;
            *(bf16x4*)&Tb[ln][lq * 32 + t * 4] = pb;
        }
        sqS = qp_xor2_add(qp_xor1_add(sqS));
        sqT = qp_xor2_add(qp_xor1_add(sqT));
        if (lq == 0) { s2[ln] = sqS; t2[ln] = sqT; }
        if (tid < N) vacc[tid] = 0.f;   // ds_add accumulator starts clean
    }

    float block_acc = 0.f;

#pragma unroll 1
    for (int fi = 0; fi < 4; ++fi) {
        if (tid < N) vshT[tid & 15][tid >> 4] = 1.0f;
        __syncthreads();   // staging/prefetch writes + vshT/vacc init visible

        // ---- GEMM: acc[j] = 16x16 tile (rows 16w.., cols 16j..) ----
        floatx4 acc[16];
#pragma unroll
        for (int j = 0; j < 16; ++j) acc[j] = (floatx4){0.f, 0.f, 0.f, 0.f};

#pragma unroll 1
        for (int kk = 0; kk < 4; ++kk) {
            bf16x8 afrag = *(const bf16x8*)&Sb[16 * w + l15][kk * 32 + q * 8];
#pragma unroll
            for (int j = 0; j < 16; ++j) {   // FULL unroll: acc[j] must stay static
                bf16x8 bfrag = *(const bf16x8*)&Tb[16 * j + l15][kk * 32 + q * 8];
                acc[j] = __builtin_amdgcn_mfma_f32_16x16x32_bf16(afrag, bfrag, acc[j], 0, 0, 0);
            }
        }

        // ---- K = exp(-cost/tau) in place. lane: rows 16w+4q+r, col 16j+l15 ----
        floatx4 s2r = *(const floatx4*)&s2[16 * w + 4 * q];
#pragma unroll
        for (int j = 0; j < 16; ++j) {
            float tc2 = t2[16 * j + l15];
#pragma unroll
            for (int r = 0; r < 4; ++r) {
                float dsq = s2r[r] + tc2 - 2.f * acc[j][r];
                float cst = sqrtf(fmaxf(dsq, 0.f));
                acc[j][r] = __expf(cst * (-1.f / TAUF));
            }
        }
        __syncthreads();   // Sb/Tb/s2/t2 free -> prefetch may write them now

        const bool pf = (fi < 3);
        const float4* Svn = (const float4*)(Sg + (fbase + fi + 1) * (size_t)(N * D));
        const float4* Tvn = (const float4*)(Tg + (fbase + fi + 1) * (size_t)(N * D));

        // ---- Sinkhorn: 10 iterations ----
        float u0 = 0.f, u1 = 0.f, u2 = 0.f, u3 = 0.f;
#pragma unroll 1
        for (int it = 0; it < NITER; ++it) {
            // u-step: row sums of K*v; v read as 4x b128 from vshT
            float rp0 = 0.f, rp1 = 0.f, rp2 = 0.f, rp3 = 0.f;
#pragma unroll
            for (int jj = 0; jj < 4; ++jj) {
                floatx4 vq = *(const floatx4*)&vshT[l15][4 * jj];
#pragma unroll
                for (int j4 = 0; j4 < 4; ++j4) {
                    const int j = 4 * jj + j4;
                    rp0 = fmaf(acc[j][0], vq[j4], rp0);
                    rp1 = fmaf(acc[j][1], vq[j4], rp1);
                    rp2 = fmaf(acc[j][2], vq[j4], rp2);
                    rp3 = fmaf(acc[j][3], vq[j4], rp3);
                }
            }
            // 16-lane butterfly, all DPP (xor1, xor2, ^7 half-mirror, ^15 mirror)
            rp0 = qp_xor1_add(rp0);  rp1 = qp_xor1_add(rp1);  rp2 = qp_xor1_add(rp2);  rp3 = qp_xor1_add(rp3);
            rp0 = qp_xor2_add(rp0);  rp1 = qp_xor2_add(rp1);  rp2 = qp_xor2_add(rp2);  rp3 = qp_xor2_add(rp3);
            rp0 = qp_xor7_add(rp0);  rp1 = qp_xor7_add(rp1);  rp2 = qp_xor7_add(rp2);  rp3 = qp_xor7_add(rp3);
            rp0 = qp_xor15_add(rp0); rp1 = qp_xor15_add(rp1); rp2 = qp_xor15_add(rp2); rp3 = qp_xor15_add(rp3);
            u0 = mu_over(rp0);
            u1 = mu_over(rp1);
            u2 = mu_over(rp2);
            u3 = mu_over(rp3);

            // prefetch issue: SLAB-CONTIGUOUS. wave = 1024B contiguous, 100% line use.
            const bool dpf = pf && (it < 8);
            float4 pa4 = {0.f, 0.f, 0.f, 0.f}, pb4 = {0.f, 0.f, 0.f, 0.f};
            if (dpf) {
                pa4 = Svn[it * 1024 + tid];
                pb4 = Tvn[it * 1024 + tid];
            }

            // v-step: col partials; reduce over quads via permlane16+permlane32 (VALU),
            // then cross-wave accumulate via ds_add_f32.
#pragma unroll
            for (int j = 0; j < 16; ++j) {
                float s = 0.f;
                s = fmaf(acc[j][0], u0, s);
                s = fmaf(acc[j][1], u1, s);
                s = fmaf(acc[j][2], u2, s);
                s = fmaf(acc[j][3], u3, s);
                s = xor16_add(s);
                s = xor32_add(s);
                if (q == 0) atomicAdd(&vacc[16 * j + l15], s);
            }

            // prefetch consume: convert -> bf16, store, in-iteration row norms.
            // p = it*1024+tid -> row p>>5 (half-wave owns a full row), cols (p&31)*4..
            if (dpf) {
                __bf16 a0 = (__bf16)pa4.x, a1 = (__bf16)pa4.y, a2 = (__bf16)pa4.z, a3 = (__bf16)pa4.w;
                __bf16 b0 = (__bf16)pb4.x, b1 = (__bf16)pb4.y, b2 = (__bf16)pb4.z, b3 = (__bf16)pb4.w;
                float fa0 = (float)a0, fa1 = (float)a1, fa2 = (float)a2, fa3 = (float)a3;
                float fb0 = (float)b0, fb1 = (float)b1, fb2 = (float)b2, fb3 = (float)b3;
                float ps = fa0 * fa0 + fa1 * fa1 + fa2 * fa2 + fa3 * fa3;
                float pt = fb0 * fb0 + fb1 * fb1 + fb2 * fb2 + fb3 * fb3;
                bf16x4 pa = {a0, a1, a2, a3};
                bf16x4 pb = {b0, b1, b2, b3};
                const int p   = it * 1024 + tid;
                const int row = p >> 5;
                const int c   = p & 31;
                *(bf16x4*)&Sb[row][c * 4] = pa;
                *(bf16x4*)&Tb[row][c * 4] = pb;
                // row norm: reduce over the 32 lanes of the half-wave (DPP + permlane16)
                ps = qp_xor1_add(ps); ps = qp_xor2_add(ps); ps = qp_xor7_add(ps); ps = qp_xor15_add(ps);
                ps = xor16_add(ps);
                pt = qp_xor1_add(pt); pt = qp_xor2_add(pt); pt = qp_xor7_add(pt); pt = qp_xor15_add(pt);
                pt = xor16_add(pt);
                if ((tid & 31) == 0) { s2[row] = ps; t2[row] = pt; }
            }

            __syncthreads();
            if (tid < N) {
                float ssum = vacc[tid];
                vacc[tid] = 0.f;                       // re-zero for next iteration/frame
                vshT[tid & 15][tid >> 4] = mu_over(ssum);
            }
            __syncthreads();
        }

        // ---- final: sum u_n K_nm v_m cost_nm ; cost = -tau*log(K) ----
        float fsum = 0.f;
#pragma unroll
        for (int jj = 0; jj < 4; ++jj) {
            floatx4 vq = *(const floatx4*)&vshT[l15][4 * jj];
#pragma unroll
            for (int j4 = 0; j4 < 4; ++j4) {
                const int j = 4 * jj + j4;
                {
                    float K0 = acc[j][0]; float c0 = -TAUF * __logf(K0); fsum += u0 * K0 * vq[j4] * c0;
                    float K1 = acc[j][1]; float c1 = -TAUF * __logf(K1); fsum += u1 * K1 * vq[j4] * c1;
                    float K2 = acc[j][2]; float c2 = -TAUF * __logf(K2); fsum += u2 * K2 * vq[j4] * c2;
                    float K3 = acc[j][3]; float c3 = -TAUF * __logf(K3); fsum += u3 * K3 * vq[j4] * c3;
                }
            }
        }
        fsum = qp_xor1_add(fsum);
        fsum = qp_xor2_add(fsum);
        fsum = qp_xor7_add(fsum);
        fsum = qp_xor15_add(fsum);
        fsum = xor16_add(fsum);
        fsum = xor32_add(fsum);
        if (lane == 0) wsum[w] = fsum;
        __syncthreads();   // also end-of-frame barrier (vshT/Sb reads all done above)
        if (tid == 0) {
            float s = 0.f;
#pragma unroll
            for (int ww = 0; ww < 16; ++ww) s += wsum[ww];
            block_acc += s;
        }
    }

    if (tid == 0) atomicAdd(out, block_acc * (1.0f / 1024.0f));
}

extern "C" void kernel_launch(void* const* d_in, const int* in_sizes, int n_in,
                              void* d_out, int out_size, void* d_ws, size_t ws_size,
                              hipStream_t stream) {
    const float* S = (const float*)d_in[0];
    const float* T = (const float*)d_in[1];
    float* out = (float*)d_out;
    hipMemsetAsync(out, 0, sizeof(float), stream);
    sinkhorn_kernel<<<dim3(256), dim3(1024), 0, stream>>>(S, T, out);
}

// Round 5
// 404.195 us; speedup vs baseline: 1.3426x; 1.3426x over previous
//
#include <hip/hip_runtime.h>

// Sinkhorn matching loss: B=16,T=64,N=256,D=128; 1024 frames.
// PERSISTENT version: 256 blocks (1/CU), each block processes 4 frames.
// Per frame: stage S,T bf16 in LDS; cdist via mfma_f32_16x16x32_bf16; K=exp(-cost/tau)
// in regs (acc[16] f32x4 / wave row-block); 10 Sinkhorn iters; final <uKv,cost>.
//
// Round-8 (round-7 post-mortem): ds_add_f32 colsum was a 16-wave SAME-ADDRESS
// serialization per j-step -> 274->380us, VALUBusy 61->45%. Revert colsum to
// contention-free red[w][...] stores (round-6 scheme). KEEP the verified
// round-7 swaps: all-DPP u-butterfly (xor1/2 quad_perm + ^7 half-mirror +
// ^15 mirror), permlane16/32 swaps, v_rcp for MUF/(x+EPS). NEW: distributed
// tail - all 16 waves reduce their own 16 columns (4 reads + xor16/32) instead
// of 4 waves doing 16 serial reads; red padded [16][258] so the 4-q column
// reads are 2-way (free).
//
// HARD RULES:
//  - every loop indexing acc[] fully unrolled (runtime index -> scratch).
//  - register budget: 64 acc (AGPR) + arch VGPR <= 128 total (4 waves/EU cap).
//    NO vector state may live across a sinkhorn iteration boundary.
//  - NO same-address LDS atomics across waves (round-7 lesson).

typedef __bf16 bf16x8 __attribute__((ext_vector_type(8)));
typedef __bf16 bf16x4 __attribute__((ext_vector_type(4)));
typedef float floatx4 __attribute__((ext_vector_type(4)));

constexpr int N = 256;
constexpr int D = 128;
constexpr int NITER = 10;
#define TAUF 0.05f
#define EPSF 1e-8f
#define MUF  (1.0f / 256.0f)

constexpr int SRW = 136;              // bf16 row stride: rows step 4 banks -> 2-way (free)
constexpr int STAGE_B = N * SRW * 2;  // 69632 bytes per staged array
constexpr int VPAD = 20;              // vshT row stride (floats): 80B, 16B-aligned, 2-way banks
constexpr int RPAD = 258;             // red row stride: 258%32=2 -> 4-q column reads 2-way (free)

__device__ __forceinline__ float bc_f(int x) { return __builtin_bit_cast(float, x); }
__device__ __forceinline__ int   bc_i(float x) { return __builtin_bit_cast(int, x); }

// xor1 within quads: quad_perm [1,0,3,2] = 0xB1. Pure VALU (DPP).
__device__ __forceinline__ float qp_xor1_add(float v) {
    return v + bc_f(__builtin_amdgcn_update_dpp(0, bc_i(v), 0xB1, 0xF, 0xF, true));
}
// xor2 within quads: quad_perm [2,3,0,1] = 0x4E.
__device__ __forceinline__ float qp_xor2_add(float v) {
    return v + bc_f(__builtin_amdgcn_update_dpp(0, bc_i(v), 0x4E, 0xF, 0xF, true));
}
// l^7 within octets: DPP ROW_HALF_MIRROR (0x141).
__device__ __forceinline__ float qp_xor7_add(float v) {
    return v + bc_f(__builtin_amdgcn_update_dpp(0, bc_i(v), 0x141, 0xF, 0xF, true));
}
// l^15 within rows of 16: DPP ROW_MIRROR (0x140).
__device__ __forceinline__ float qp_xor15_add(float v) {
    return v + bc_f(__builtin_amdgcn_update_dpp(0, bc_i(v), 0x140, 0xF, 0xF, true));
}
// ds_swizzle fallback (BitMode): (mask<<10)|0x1F
template <int PAT>
__device__ __forceinline__ float swz_xor_add(float v) {
    return v + bc_f(__builtin_amdgcn_ds_swizzle(bc_i(v), PAT));
}
// xor16 via permlane16_swap (VALU): r[0]+r[1] == v + v[lane^16]
__device__ __forceinline__ float xor16_add(float v) {
#if __has_builtin(__builtin_amdgcn_permlane16_swap)
    auto r = __builtin_amdgcn_permlane16_swap(bc_i(v), bc_i(v), false, false);
    return bc_f(r[0]) + bc_f(r[1]);
#else
    return swz_xor_add<0x401F>(v);
#endif
}
// xor32 via permlane32_swap (VALU): r[0]+r[1] == v + v[lane^32]
__device__ __forceinline__ float xor32_add(float v) {
    auto r = __builtin_amdgcn_permlane32_swap(bc_i(v), bc_i(v), false, false);
    return bc_f(r[0]) + bc_f(r[1]);
}
// MUF/(x+EPS) via v_rcp_f32 (~1ulp) + exact *2^-8 scale
__device__ __forceinline__ float mu_over(float x) {
#if __has_builtin(__builtin_amdgcn_rcpf)
    return MUF * __builtin_amdgcn_rcpf(x + EPSF);
#else
    return MUF / (x + EPSF);
#endif
}

__global__ __launch_bounds__(1024) __attribute__((amdgpu_waves_per_eu(4, 4)))
void sinkhorn_kernel(const float* __restrict__ Sg, const float* __restrict__ Tg,
                     float* __restrict__ out)
{
    __shared__ __align__(16) char stage[2 * STAGE_B];   // Sb,Tb (live across frames: prefetch target)
    __shared__ __align__(16) float red[16][RPAD];       // colsum partials (padded: see RPAD)
    __shared__ __align__(16) float vshT[16][VPAD];      // v transposed: vshT[c&15][c>>4]
    __shared__ float s2[N], t2[N], wsum[16];

    __bf16 (*Sb)[SRW] = (__bf16(*)[SRW])stage;
    __bf16 (*Tb)[SRW] = (__bf16(*)[SRW])(stage + STAGE_B);

    const int tid  = threadIdx.x;
    const int lane = tid & 63;
    const int w    = tid >> 6;     // wave 0..15 -> K rows [16w, 16w+16)
    const int l15  = lane & 15;
    const int q    = lane >> 4;    // quad 0..3
    const int ln   = tid >> 2;     // frame-0 staging row 0..255
    const int lq   = tid & 3;      // frame-0 staging d-chunk of 32 floats

    const size_t fbase = (size_t)blockIdx.x * 4;

    // ---- frame 0: direct staging (chunks back-to-back: full line reuse) ----
    {
        const float4* Sv = (const float4*)(Sg + fbase * (size_t)(N * D));
        const float4* Tv = (const float4*)(Tg + fbase * (size_t)(N * D));
        float sqS = 0.f, sqT = 0.f;
#pragma unroll 2
        for (int t = 0; t < 8; ++t) {
            float4 a = Sv[ln * 32 + lq * 8 + t];
            float4 b = Tv[ln * 32 + lq * 8 + t];
            __bf16 a0 = (__bf16)a.x, a1 = (__bf16)a.y, a2 = (__bf16)a.z, a3 = (__bf16)a.w;
            __bf16 b0 = (__bf16)b.x, b1 = (__bf16)b.y, b2 = (__bf16)b.z, b3 = (__bf16)b.w;
            float fa0 = (float)a0, fa1 = (float)a1, fa2 = (float)a2, fa3 = (float)a3;
            float fb0 = (float)b0, fb1 = (float)b1, fb2 = (float)b2, fb3 = (float)b3;
            sqS += fa0 * fa0 + fa1 * fa1 + fa2 * fa2 + fa3 * fa3;
            sqT += fb0 * fb0 + fb1 * fb1 + fb2 * fb2 + fb3 * fb3;
            bf16x4 pa = {a0, a1, a2, a3};
            bf16x4 pb = {b0, b1, b2, b3};
            *(bf16x4*)&Sb[ln][lq * 32 + t * 4] = pa;
            *(bf16x4*)&Tb[ln][lq * 32 + t * 4] = pb;
        }
        sqS = qp_xor2_add(qp_xor1_add(sqS));
        sqT = qp_xor2_add(qp_xor1_add(sqT));
        if (lq == 0) { s2[ln] = sqS; t2[ln] = sqT; }
    }

    float block_acc = 0.f;

#pragma unroll 1
    for (int fi = 0; fi < 4; ++fi) {
        if (tid < N) vshT[tid & 15][tid >> 4] = 1.0f;
        __syncthreads();   // staging/prefetch writes + vshT init visible

        // ---- GEMM: acc[j] = 16x16 tile (rows 16w.., cols 16j..) ----
        floatx4 acc[16];
#pragma unroll
        for (int j = 0; j < 16; ++j) acc[j] = (floatx4){0.f, 0.f, 0.f, 0.f};

#pragma unroll 1
        for (int kk = 0; kk < 4; ++kk) {
            bf16x8 afrag = *(const bf16x8*)&Sb[16 * w + l15][kk * 32 + q * 8];
#pragma unroll
            for (int j = 0; j < 16; ++j) {   // FULL unroll: acc[j] must stay static
                bf16x8 bfrag = *(const bf16x8*)&Tb[16 * j + l15][kk * 32 + q * 8];
                acc[j] = __builtin_amdgcn_mfma_f32_16x16x32_bf16(afrag, bfrag, acc[j], 0, 0, 0);
            }
        }

        // ---- K = exp(-cost/tau) in place. lane: rows 16w+4q+r, col 16j+l15 ----
        floatx4 s2r = *(const floatx4*)&s2[16 * w + 4 * q];
#pragma unroll
        for (int j = 0; j < 16; ++j) {
            float tc2 = t2[16 * j + l15];
#pragma unroll
            for (int r = 0; r < 4; ++r) {
                float dsq = s2r[r] + tc2 - 2.f * acc[j][r];
                float cst = sqrtf(fmaxf(dsq, 0.f));
                acc[j][r] = __expf(cst * (-1.f / TAUF));
            }
        }
        __syncthreads();   // Sb/Tb/s2/t2 free -> prefetch may write them now

        const bool pf = (fi < 3);
        const float4* Svn = (const float4*)(Sg + (fbase + fi + 1) * (size_t)(N * D));
        const float4* Tvn = (const float4*)(Tg + (fbase + fi + 1) * (size_t)(N * D));

        // ---- Sinkhorn: 10 iterations ----
        float u0 = 0.f, u1 = 0.f, u2 = 0.f, u3 = 0.f;
#pragma unroll 1
        for (int it = 0; it < NITER; ++it) {
            // u-step: row sums of K*v; v read as 4x b128 from vshT
            float rp0 = 0.f, rp1 = 0.f, rp2 = 0.f, rp3 = 0.f;
#pragma unroll
            for (int jj = 0; jj < 4; ++jj) {
                floatx4 vq = *(const floatx4*)&vshT[l15][4 * jj];
#pragma unroll
                for (int j4 = 0; j4 < 4; ++j4) {
                    const int j = 4 * jj + j4;
                    rp0 = fmaf(acc[j][0], vq[j4], rp0);
                    rp1 = fmaf(acc[j][1], vq[j4], rp1);
                    rp2 = fmaf(acc[j][2], vq[j4], rp2);
                    rp3 = fmaf(acc[j][3], vq[j4], rp3);
                }
            }
            // 16-lane butterfly, all DPP (xor1, xor2, ^7 half-mirror, ^15 mirror)
            rp0 = qp_xor1_add(rp0);  rp1 = qp_xor1_add(rp1);  rp2 = qp_xor1_add(rp2);  rp3 = qp_xor1_add(rp3);
            rp0 = qp_xor2_add(rp0);  rp1 = qp_xor2_add(rp1);  rp2 = qp_xor2_add(rp2);  rp3 = qp_xor2_add(rp3);
            rp0 = qp_xor7_add(rp0);  rp1 = qp_xor7_add(rp1);  rp2 = qp_xor7_add(rp2);  rp3 = qp_xor7_add(rp3);
            rp0 = qp_xor15_add(rp0); rp1 = qp_xor15_add(rp1); rp2 = qp_xor15_add(rp2); rp3 = qp_xor15_add(rp3);
            u0 = mu_over(rp0);
            u1 = mu_over(rp1);
            u2 = mu_over(rp2);
            u3 = mu_over(rp3);

            // prefetch issue: SLAB-CONTIGUOUS. wave = 1024B contiguous, 100% line use.
            const bool dpf = pf && (it < 8);
            float4 pa4 = {0.f, 0.f, 0.f, 0.f}, pb4 = {0.f, 0.f, 0.f, 0.f};
            if (dpf) {
                pa4 = Svn[it * 1024 + tid];
                pb4 = Tvn[it * 1024 + tid];
            }

            // v-step: col partials; sum over quads via permlane16+permlane32 (VALU);
            // per-wave result -> red[w][...] (distinct addresses: NO contention).
#pragma unroll
            for (int j = 0; j < 16; ++j) {
                float s = 0.f;
                s = fmaf(acc[j][0], u0, s);
                s = fmaf(acc[j][1], u1, s);
                s = fmaf(acc[j][2], u2, s);
                s = fmaf(acc[j][3], u3, s);
                s = xor16_add(s);
                s = xor32_add(s);
                if (q == 0) red[w][16 * j + l15] = s;
            }

            // prefetch consume: convert -> bf16, store, in-iteration row norms.
            // p = it*1024+tid -> row p>>5 (half-wave owns a full row), cols (p&31)*4..
            if (dpf) {
                __bf16 a0 = (__bf16)pa4.x, a1 = (__bf16)pa4.y, a2 = (__bf16)pa4.z, a3 = (__bf16)pa4.w;
                __bf16 b0 = (__bf16)pb4.x, b1 = (__bf16)pb4.y, b2 = (__bf16)pb4.z, b3 = (__bf16)pb4.w;
                float fa0 = (float)a0, fa1 = (float)a1, fa2 = (float)a2, fa3 = (float)a3;
                float fb0 = (float)b0, fb1 = (float)b1, fb2 = (float)b2, fb3 = (float)b3;
                float ps = fa0 * fa0 + fa1 * fa1 + fa2 * fa2 + fa3 * fa3;
                float pt = fb0 * fb0 + fb1 * fb1 + fb2 * fb2 + fb3 * fb3;
                bf16x4 pa = {a0, a1, a2, a3};
                bf16x4 pb = {b0, b1, b2, b3};
                const int p   = it * 1024 + tid;
                const int row = p >> 5;
                const int c   = p & 31;
                *(bf16x4*)&Sb[row][c * 4] = pa;
                *(bf16x4*)&Tb[row][c * 4] = pb;
                // row norm: reduce over the 32 lanes of the half-wave (DPP + permlane16)
                ps = qp_xor1_add(ps); ps = qp_xor2_add(ps); ps = qp_xor7_add(ps); ps = qp_xor15_add(ps);
                ps = xor16_add(ps);
                pt = qp_xor1_add(pt); pt = qp_xor2_add(pt); pt = qp_xor7_add(pt); pt = qp_xor15_add(pt);
                pt = xor16_add(pt);
                if ((tid & 31) == 0) { s2[row] = ps; t2[row] = pt; }
            }

            __syncthreads();
            // distributed tail: wave w reduces its own 16 columns (c = 16w+l15).
            // lane (q,l15) reads 4 partials, tree-add, then sum across q in-wave.
            {
                float p0 = red[4 * q + 0][16 * w + l15];
                float p1 = red[4 * q + 1][16 * w + l15];
                float p2 = red[4 * q + 2][16 * w + l15];
                float p3 = red[4 * q + 3][16 * w + l15];
                float ssum = (p0 + p1) + (p2 + p3);
                ssum = xor16_add(ssum);   // sum across q within 32-lane half
                ssum = xor32_add(ssum);   // sum across halves -> full colsum in all lanes
                if (q == 0) vshT[l15][w] = mu_over(ssum);
            }
            __syncthreads();
        }

        // ---- final: sum u_n K_nm v_m cost_nm ; cost = -tau*log(K) ----
        float fsum = 0.f;
#pragma unroll
        for (int jj = 0; jj < 4; ++jj) {
            floatx4 vq = *(const floatx4*)&vshT[l15][4 * jj];
#pragma unroll
            for (int j4 = 0; j4 < 4; ++j4) {
                const int j = 4 * jj + j4;
                {
                    float K0 = acc[j][0]; float c0 = -TAUF * __logf(K0); fsum += u0 * K0 * vq[j4] * c0;
                    float K1 = acc[j][1]; float c1 = -TAUF * __logf(K1); fsum += u1 * K1 * vq[j4] * c1;
                    float K2 = acc[j][2]; float c2 = -TAUF * __logf(K2); fsum += u2 * K2 * vq[j4] * c2;
                    float K3 = acc[j][3]; float c3 = -TAUF * __logf(K3); fsum += u3 * K3 * vq[j4] * c3;
                }
            }
        }
        fsum = qp_xor1_add(fsum);
        fsum = qp_xor2_add(fsum);
        fsum = qp_xor7_add(fsum);
        fsum = qp_xor15_add(fsum);
        fsum = xor16_add(fsum);
        fsum = xor32_add(fsum);
        if (lane == 0) wsum[w] = fsum;
        __syncthreads();   // also end-of-frame barrier (vshT/Sb reads all done above)
        if (tid == 0) {
            float s = 0.f;
#pragma unroll
            for (int ww = 0; ww < 16; ++ww) s += wsum[ww];
            block_acc += s;
        }
    }

    if (tid == 0) atomicAdd(out, block_acc * (1.0f / 1024.0f));
}

extern "C" void kernel_launch(void* const* d_in, const int* in_sizes, int n_in,
                              void* d_out, int out_size, void* d_ws, size_t ws_size,
                              hipStream_t stream) {
    const float* S = (const float*)d_in[0];
    const float* T = (const float*)d_in[1];
    float* out = (float*)d_out;
    hipMemsetAsync(out, 0, sizeof(float), stream);
    sinkhorn_kernel<<<dim3(256), dim3(1024), 0, stream>>>(S, T, out);
}